// Round 1
// baseline (648.395 us; speedup 1.0000x reference)
//
#include <hip/hip_runtime.h>
#include <math.h>

#define BATCH 2048
#define NCLS 62
#define TPB 512           // 8 waves; 1 block/CU (LDS-bound) -> 8 waves/CU

__device__ __forceinline__ float wave_max(float v) {
#pragma unroll
    for (int m = 32; m >= 1; m >>= 1) v = fmaxf(v, __shfl_xor(v, m, 64));
    return v;
}
__device__ __forceinline__ float wave_sum(float v) {
#pragma unroll
    for (int m = 32; m >= 1; m >>= 1) v += __shfl_xor(v, m, 64);
    return v;
}

// row r of trans -> (group, channel-within-group): inverse of _GROUPS
__device__ const unsigned char GRP_TBL[62] = {
    0,0,0,0,0, 1, 0,0,0,0,0,0,0,           // 0-12
    1,1,1,                                  // 13-15
    2,2,2,2,2,                              // 16-20
    1,1,1,1,                                // 21-24
    2,2,2,2,2,                              // 25-29
    1,1,1,1,                                // 30-33
    2,2,2,2,2,                              // 34-38
    1,1,1,1,                                // 39-42
    2,2,2,2,2,                              // 43-47
    1,1,                                    // 48-49
    3,3,3,3,3,3,3,3,3,3,3,3                 // 50-61
};
__device__ const unsigned char CHAN_TBL[62] = {
    1,0,2,3,4, 0, 5,6,7,8,9,10,11,
    1,2,3,
    0,1,2,3,4,
    4,5,6,7,
    5,6,7,8,9,
    8,9,10,11,
    10,11,12,13,14,
    12,13,14,15,
    15,16,17,18,19,
    16,17,
    0,1,2,3,4,5,6,7,8,9,10,11
};

// Fused kernel: one block per batch element.
//   Phase A: stream x1..x4 (124 KiB) into LDS while accumulating the 4 dot
//            products (x is read from HBM exactly ONCE).
//   Phase B: per-head softmax confidence (waves 0..3).
//   Combine: u = sigmoid(dot+b); nc = softmax(conf); s = u*nc.
//   Phase C: trans[b,r,:] = (x_s[grp,ch,:] + g[b,r,:]) * s[grp], x from LDS.
__global__ __launch_bounds__(TPB) void fused_kernel(
    const float4* __restrict__ x1, const float4* __restrict__ x2,
    const float4* __restrict__ x3, const float4* __restrict__ x4,
    const float4* __restrict__ g,
    const float* __restrict__ lg1, const float* __restrict__ lg2,
    const float* __restrict__ lg3, const float* __restrict__ lg4,
    const float4* __restrict__ W1, const float* __restrict__ bb1,
    const float4* __restrict__ W2, const float* __restrict__ bb2,
    const float4* __restrict__ W3, const float* __restrict__ bb3,
    const float4* __restrict__ W4, const float* __restrict__ bb4,
    float* __restrict__ out_nc, float4* __restrict__ out_trans)
{
    __shared__ float4 x_s[7936];    // 124 KiB: all 62 channels of this batch
    __shared__ float conf_s[4];
    __shared__ float part_s[8][4];  // [wave][group]
    __shared__ float s_s[4];

    const int b    = blockIdx.x;
    const int tid  = threadIdx.x;
    const int wave = tid >> 6;
    const int lane = tid & 63;

    const int fan4[4]  = {1536, 2304, 2560, 1536};  // fan_in/4 per group
    const int base4[4] = {0, 1536, 3840, 6400};     // cumulative offsets
    const float4* xv[4] = {x1, x2, x3, x4};
    const float4* wv[4] = {W1, W2, W3, W4};

    // ---- phase A: x -> LDS + dot partials (the big HBM read; issue first) ----
    float acc0 = 0.f, acc1 = 0.f, acc2 = 0.f, acc3 = 0.f;
#pragma unroll
    for (int i = 0; i < 4; ++i) {
        const float4* xp = xv[i] + (size_t)b * fan4[i];
        const float4* wp = wv[i];
        float a = 0.f;
#pragma unroll 4
        for (int j = tid; j < fan4[i]; j += TPB) {
            float4 xx = xp[j];
            float4 ww = wp[j];
            x_s[base4[i] + j] = xx;
            a += xx.x * ww.x + xx.y * ww.y + xx.z * ww.z + xx.w * ww.w;
        }
        if (i == 0) acc0 = a; else if (i == 1) acc1 = a;
        else if (i == 2) acc2 = a; else acc3 = a;
    }
    {
        float a0 = wave_sum(acc0);
        float a1 = wave_sum(acc1);
        float a2 = wave_sum(acc2);
        float a3 = wave_sum(acc3);
        if (lane == 0) {
            part_s[wave][0] = a0; part_s[wave][1] = a1;
            part_s[wave][2] = a2; part_s[wave][3] = a3;
        }
    }

    // ---- phase B: confidence per head; wave w (0..3) handles logits_{w+1} ----
    if (wave < 4) {
        const float* lg = (wave == 0) ? lg1 : (wave == 1) ? lg2
                        : (wave == 2) ? lg3 : lg4;
        float v = (lane < NCLS) ? lg[b * NCLS + lane] : -INFINITY;
        float m = wave_max(v);
        float e = (lane < NCLS) ? __expf(v - m) : 0.0f;
        float S = wave_sum(e);
        float p = e / S;
        float t = (lane < NCLS) ? p * __logf(p + 1e-8f) : 0.0f;
        float ent = -wave_sum(t);
        // max_p = 1/S ; norm_ent = ent/ln(62), 1/ln(62)=0.242298797
        float conf = (1.0f / S) * (1.0f - ent * 0.242298797f);
        if (lane == 0) conf_s[wave] = conf;
    }
    __syncthreads();

    // ---- combine: u, softmax over confidences, scales ----
    if (tid < 4) {
        const int i = tid;
        float dot = 0.f;
#pragma unroll
        for (int w = 0; w < 8; ++w) dot += part_s[w][i];
        float bias = (i == 0) ? bb1[0] : (i == 1) ? bb2[0]
                   : (i == 2) ? bb3[0] : bb4[0];
        float u = 1.0f / (1.0f + __expf(-(dot + bias)));
        float c0 = conf_s[0], c1 = conf_s[1], c2 = conf_s[2], c3 = conf_s[3];
        float m4 = fmaxf(fmaxf(c0, c1), fmaxf(c2, c3));
        float e0 = __expf(c0 - m4), e1 = __expf(c1 - m4);
        float e2 = __expf(c2 - m4), e3 = __expf(c3 - m4);
        float S4 = e0 + e1 + e2 + e3;
        float ei = (i == 0) ? e0 : (i == 1) ? e1 : (i == 2) ? e2 : e3;
        float nc = ei / S4;
        out_nc[i * BATCH + b] = nc;     // outputs 0..3, each (B,1)
        s_s[i] = u * nc;
    }
    __syncthreads();

    // ---- phase C: trans rows from LDS-staged x + streamed g ----
    const float4* gp = g + (size_t)b * 7936;
    float4*       op = out_trans + (size_t)b * 7936;
#pragma unroll 4
    for (int k = 0; k < 16; ++k) {
        int idx = tid + k * TPB;        // 7936 = 15*512 + 256
        if (idx < 7936) {
            int row = idx >> 7;         // 0..61
            int d4  = idx & 127;
            int grp = GRP_TBL[row];
            int ch  = CHAN_TBL[row];
            float sc = s_s[grp];
            float4 xx = x_s[base4[grp] + ch * 128 + d4];
            float4 gg = gp[idx];
            float4 o;
            o.x = (xx.x + gg.x) * sc;
            o.y = (xx.y + gg.y) * sc;
            o.z = (xx.z + gg.z) * sc;
            o.w = (xx.w + gg.w) * sc;
            op[idx] = o;
        }
    }
}

extern "C" void kernel_launch(void* const* d_in, const int* in_sizes, int n_in,
                              void* d_out, int out_size, void* d_ws, size_t ws_size,
                              hipStream_t stream) {
    const float* x1  = (const float*)d_in[0];
    const float* x2  = (const float*)d_in[1];
    const float* x3  = (const float*)d_in[2];
    const float* x4  = (const float*)d_in[3];
    const float* g   = (const float*)d_in[4];
    const float* lg1 = (const float*)d_in[5];
    const float* lg2 = (const float*)d_in[6];
    const float* lg3 = (const float*)d_in[7];
    const float* lg4 = (const float*)d_in[8];
    const float* W1  = (const float*)d_in[9];
    const float* b1  = (const float*)d_in[10];
    const float* W2  = (const float*)d_in[11];
    const float* b2  = (const float*)d_in[12];
    const float* W3  = (const float*)d_in[13];
    const float* b3  = (const float*)d_in[14];
    const float* W4  = (const float*)d_in[15];
    const float* b4  = (const float*)d_in[16];

    float* out = (float*)d_out;
    // trans output starts after the four (B,1) outputs: offset 4*2048 floats
    float4* out_trans = (float4*)(out + 4 * BATCH);

    fused_kernel<<<BATCH, TPB, 0, stream>>>(
        (const float4*)x1, (const float4*)x2, (const float4*)x3, (const float4*)x4,
        (const float4*)g,
        lg1, lg2, lg3, lg4,
        (const float4*)W1, b1, (const float4*)W2, b2,
        (const float4*)W3, b3, (const float4*)W4, b4,
        out, out_trans);
}

// Round 2
// 619.421 us; speedup vs baseline: 1.0468x; 1.0468x over previous
//
#include <hip/hip_runtime.h>
#include <math.h>

#define BATCH 2048
#define NCLS 62
#define TPB 256   // 4 waves per block; one (batch, group) pair per block

__device__ __forceinline__ float wave_max(float v) {
#pragma unroll
    for (int m = 32; m >= 1; m >>= 1) v = fmaxf(v, __shfl_xor(v, m, 64));
    return v;
}
__device__ __forceinline__ float wave_sum(float v) {
#pragma unroll
    for (int m = 32; m >= 1; m >>= 1) v += __shfl_xor(v, m, 64);
    return v;
}

// trans row for (group, channel): ROWS_TBL[grp][ch] = _GROUPS[grp][ch] (0-based)
__device__ const unsigned char ROWS_TBL[4][20] = {
    { 1, 0, 2, 3, 4, 6, 7, 8, 9,10,11,12,  0,0,0,0,0,0,0,0},
    { 5,13,14,15,21,22,23,24,30,31,32,33, 39,40,41,42,48,49, 0,0},
    {16,17,18,19,20,25,26,27,28,29,34,35, 36,37,38,43,44,45,46,47},
    {50,51,52,53,54,55,56,57,58,59,60,61,  0,0,0,0,0,0,0,0}
};

// One block per (batch, group). Fully independent:
//   Phase A: x_grp -> registers (<=10 float4/thread) + dot partial.
//   Phase B: 4 softmax confidences from logits (waves 0..3, redundant per block).
//   Combine: u = sigmoid(dot+b), nc = softmax(conf), s = u*nc[grp].
//   Phase C: out[row(ch),d] = (x_reg + g[row(ch),d]) * s  -- permuted register writeback.
__global__ __launch_bounds__(TPB) void fused_kernel(
    const float4* __restrict__ x1, const float4* __restrict__ x2,
    const float4* __restrict__ x3, const float4* __restrict__ x4,
    const float4* __restrict__ g,
    const float* __restrict__ lg1, const float* __restrict__ lg2,
    const float* __restrict__ lg3, const float* __restrict__ lg4,
    const float4* __restrict__ W1, const float* __restrict__ bb1,
    const float4* __restrict__ W2, const float* __restrict__ bb2,
    const float4* __restrict__ W3, const float* __restrict__ bb3,
    const float4* __restrict__ W4, const float* __restrict__ bb4,
    float* __restrict__ out_nc, float4* __restrict__ out_trans)
{
    const int bid  = blockIdx.x;
    const int b    = bid >> 2;
    const int grp  = bid & 3;
    const int tid  = threadIdx.x;
    const int wave = tid >> 6;
    const int lane = tid & 63;

    __shared__ float conf_s[4];
    __shared__ float part_s[4];
    __shared__ float s_sh;

    const int fan4_tbl[4] = {1536, 2304, 2560, 1536};   // fan_in/4 per group
    const int nj_tbl[4]   = {6, 9, 10, 6};              // float4 per thread
    const float4* xs = (grp == 0) ? x1 : (grp == 1) ? x2 : (grp == 2) ? x3 : x4;
    const float4* ws = (grp == 0) ? W1 : (grp == 1) ? W2 : (grp == 2) ? W3 : W4;
    const int fan4 = fan4_tbl[grp];
    const int nj   = nj_tbl[grp];

    // ---- phase A: x -> registers + dot partial (x read from HBM exactly once) ----
    float4 xr[10];
    const float4* xp = xs + (size_t)b * fan4;
    float a = 0.f;
#pragma unroll
    for (int k = 0; k < 10; ++k) {
        if (k < nj) {
            int j = tid + k * TPB;
            float4 xx = xp[j];
            float4 ww = ws[j];
            xr[k] = xx;
            a += xx.x * ww.x + xx.y * ww.y + xx.z * ww.z + xx.w * ww.w;
        }
    }
    a = wave_sum(a);
    if (lane == 0) part_s[wave] = a;

    // ---- phase B: confidence for head 'wave' (waves 0..3) ----
    {
        const float* lg = (wave == 0) ? lg1 : (wave == 1) ? lg2
                        : (wave == 2) ? lg3 : lg4;
        float v = (lane < NCLS) ? lg[b * NCLS + lane] : -INFINITY;
        float m = wave_max(v);
        float e = (lane < NCLS) ? __expf(v - m) : 0.0f;
        float S = wave_sum(e);
        float p = e / S;
        float t = (lane < NCLS) ? p * __logf(p + 1e-8f) : 0.0f;
        float ent = -wave_sum(t);
        // max_p = 1/S ; norm_ent = ent/ln(62), 1/ln(62) = 0.242298797
        float conf = (1.0f / S) * (1.0f - ent * 0.242298797f);
        if (lane == 0) conf_s[wave] = conf;
    }
    __syncthreads();

    // ---- combine: u, softmax over the 4 confidences, this group's scale ----
    if (tid == 0) {
        float dot = part_s[0] + part_s[1] + part_s[2] + part_s[3];
        float bias = (grp == 0) ? bb1[0] : (grp == 1) ? bb2[0]
                   : (grp == 2) ? bb3[0] : bb4[0];
        float u = 1.0f / (1.0f + __expf(-(dot + bias)));
        float c0 = conf_s[0], c1 = conf_s[1], c2 = conf_s[2], c3 = conf_s[3];
        float m4 = fmaxf(fmaxf(c0, c1), fmaxf(c2, c3));
        float e0 = __expf(c0 - m4), e1 = __expf(c1 - m4);
        float e2 = __expf(c2 - m4), e3 = __expf(c3 - m4);
        float S4 = e0 + e1 + e2 + e3;
        float eg = (grp == 0) ? e0 : (grp == 1) ? e1 : (grp == 2) ? e2 : e3;
        s_sh = u * (eg / S4);
        if (grp == 0) {      // one block per batch writes the 4 nc outputs
            out_nc[0 * BATCH + b] = e0 / S4;
            out_nc[1 * BATCH + b] = e1 / S4;
            out_nc[2 * BATCH + b] = e2 / S4;
            out_nc[3 * BATCH + b] = e3 / S4;
        }
    }
    __syncthreads();
    const float sc = s_sh;

    // ---- phase C: permuted register writeback, g streamed ----
    const float4* gp = g + (size_t)b * 7936;        // 62*128 float4 per batch
    float4*       op = out_trans + (size_t)b * 7936;
#pragma unroll
    for (int k = 0; k < 10; ++k) {
        if (k < nj) {
            int j   = tid + k * TPB;
            int ch  = j >> 7;                        // 128 float4 per channel
            int d4  = j & 127;
            int row = ROWS_TBL[grp][ch];
            int o   = row * 128 + d4;
            float4 gg = gp[o];
            float4 xx = xr[k];
            float4 oo;
            oo.x = (xx.x + gg.x) * sc;
            oo.y = (xx.y + gg.y) * sc;
            oo.z = (xx.z + gg.z) * sc;
            oo.w = (xx.w + gg.w) * sc;
            op[o] = oo;
        }
    }
}

extern "C" void kernel_launch(void* const* d_in, const int* in_sizes, int n_in,
                              void* d_out, int out_size, void* d_ws, size_t ws_size,
                              hipStream_t stream) {
    const float* x1  = (const float*)d_in[0];
    const float* x2  = (const float*)d_in[1];
    const float* x3  = (const float*)d_in[2];
    const float* x4  = (const float*)d_in[3];
    const float* g   = (const float*)d_in[4];
    const float* lg1 = (const float*)d_in[5];
    const float* lg2 = (const float*)d_in[6];
    const float* lg3 = (const float*)d_in[7];
    const float* lg4 = (const float*)d_in[8];
    const float* W1  = (const float*)d_in[9];
    const float* b1  = (const float*)d_in[10];
    const float* W2  = (const float*)d_in[11];
    const float* b2  = (const float*)d_in[12];
    const float* W3  = (const float*)d_in[13];
    const float* b3  = (const float*)d_in[14];
    const float* W4  = (const float*)d_in[15];
    const float* b4  = (const float*)d_in[16];

    float* out = (float*)d_out;
    // trans output starts after the four (B,1) outputs: offset 4*2048 floats
    float4* out_trans = (float4*)(out + 4 * BATCH);

    fused_kernel<<<BATCH * 4, TPB, 0, stream>>>(
        (const float4*)x1, (const float4*)x2, (const float4*)x3, (const float4*)x4,
        (const float4*)g,
        lg1, lg2, lg3, lg4,
        (const float4*)W1, b1, (const float4*)W2, b2,
        (const float4*)W3, b3, (const float4*)W4, b4,
        out, out_trans);
}